// Round 4
// baseline (258.038 us; speedup 1.0000x reference)
//
#include <hip/hip_runtime.h>

// Octree cross-entropy loss.
// D=256, BS=16 -> 4096 level-0 tiles of 16^3 voxels.
// Level 0: per-voxel 2-class CE, mean over tile, summed over tiles.
// Levels 1..4 (b = 32,64,128,256): 3-class CE (pure0/pure1/mixed) * b^3,
// class derived from per-16^3-tile popcounts of gt01 aggregated upward.
//
// R6 -> R7 changes:
//  - R3..R6 (one-shot reg loads / wide reg prefetch / barrier global_load_lds
//    / persistent zero-barrier DMA pipeline) ALL pinned at ~1650 GB/s. Each
//    had either a forced vmcnt drain (R5 barrier; R6's gcur=gnxt register
//    copy after the last-issued gt loads == vmcnt(0)) or a VGPR cliff that
//    serialized loads (R3/R4). R7 uses the one shape proven to reach ~6.3
//    TB/s on this chip (m13 copy / fillBuffer): max-occupancy grid-stride
//    loop, no LDS staging, no DMA, no barriers, independent iterations the
//    compiler can modulo-schedule at low VGPR.
//  - logits read with __builtin_nontemporal_load (read-once stream; avoids
//    LLC allocation churn, keeps gt LLC-resident).
//  - Per-tile reduction: wave-contiguous mapping (a wave's 64 lanes always
//    share one tile) -> wave shuffle-reduce, lane0 scatter-writes
//    partial16[tile*16+slot] / cnt16[...]; each slot written exactly once
//    (no atomics, no workspace zeroing, deterministic). levels_kernel folds
//    the 16-slot sums.

typedef float v4f __attribute__((ext_vector_type(4)));

__device__ __forceinline__ float softplus(float x) {
    // log(1 + e^x), stable
    return fmaxf(x, 0.f) + __logf(1.f + __expf(-fabsf(x)));
}

__device__ __forceinline__ float nll3(const float* __restrict__ l, int c) {
    float a = l[0], b = l[1], d = l[2];
    float m = fmaxf(fmaxf(a, b), d);
    float lse = m + __logf(__expf(a - m) + __expf(b - m) + __expf(d - m));
    return lse - l[c];
}

// 2048 blocks x 256 threads, 8 grid-stride iterations each.
// Unit u (0..4194303) = one float4-pair = 4 voxels: tile = u>>10, off = u&1023.
__global__ __launch_bounds__(256, 8) void level0_kernel(
    const int* __restrict__ gt,        // [256^3], values +-1, x-major (x,y,z)
    const float* __restrict__ logits,  // [4096, 2, 4096]
    float* __restrict__ partial16,     // [4096*16] per-(tile,slot) scaled NLL sums
    int* __restrict__ cnt16)           // [4096*16] per-(tile,slot) popcounts
{
    const int tid0 = blockIdx.x * 256 + threadIdx.x;
    const int lane = threadIdx.x & 63;
    constexpr int NTH = 2048 * 256;    // 524288 threads

#pragma unroll
    for (int it = 0; it < 8; ++it) {
        const int u    = it * NTH + tid0;
        const int tile = u >> 10;
        const int off  = u & 1023;

        const v4f a = __builtin_nontemporal_load(
            reinterpret_cast<const v4f*>(logits + (size_t)tile * 8192 + off * 4));
        const v4f b = __builtin_nontemporal_load(
            reinterpret_cast<const v4f*>(logits + (size_t)tile * 8192 + 4096 + off * 4));

        // gt for voxels v = off*4 .. off*4+3 of this tile (4 consecutive z)
        const int bx = tile >> 8, by = (tile >> 4) & 15, bz = tile & 15;
        const int v  = off << 2;
        const int ix = v >> 8, iy = (v >> 4) & 15, iz = v & 15;
        const int gidx = ((bx * 16 + ix) << 16) + ((by * 16 + iy) << 8)
                       + (bz * 16 + iz);
        const int4 g = *reinterpret_cast<const int4*>(gt + gidx);

        // 2-class CE: tgt=1 -> softplus(l0-l1); tgt=0 -> softplus(l1-l0)
        const float dx = a.x - b.x;
        const float dy = a.y - b.y;
        const float dz = a.z - b.z;
        const float dw = a.w - b.w;
        const int t0 = g.x > 0, t1 = g.y > 0, t2 = g.z > 0, t3 = g.w > 0;
        int   on = t0 + t1 + t2 + t3;
        float ls = softplus(t0 ? dx : -dx)
                 + softplus(t1 ? dy : -dy)
                 + softplus(t2 ? dz : -dz)
                 + softplus(t3 ? dw : -dw);

        // wave owns 64 consecutive u -> single tile; reduce and scatter
#pragma unroll
        for (int d = 32; d > 0; d >>= 1) {
            ls += __shfl_down(ls, d, 64);
            on += __shfl_down(on, d, 64);
        }
        if (lane == 0) {
            const int slot = (u >> 6) & 15;        // 16 wave-runs per tile
            partial16[tile * 16 + slot] = ls * (1.0f / 4096.0f);
            cnt16[tile * 16 + slot]     = on;
        }
    }
}

// Single block, 512 threads: fold 16-way slots, reduce level-0 partials,
// hierarchical popcount aggregation, 3-class CE for levels 1..4, write out[0].
__global__ __launch_bounds__(512) void levels_kernel(
    const float* __restrict__ partial16, // [4096*16]
    const int* __restrict__ cnt16,       // [4096*16]
    const float* __restrict__ l1,        // [512,3]
    const float* __restrict__ l2,        // [64,3]
    const float* __restrict__ l3,        // [8,3]
    const float* __restrict__ l4,        // [1,3]
    float* __restrict__ out)
{
    __shared__ int   s0[4096];   // per-tile popcounts (16 KB)
    __shared__ int   s1[512];
    __shared__ int   s2[64];
    __shared__ int   s3[8];
    __shared__ float red[512];
    const int tid = threadIdx.x;
    float contrib = 0.f;

    // fold 16 slots per tile; 8 tiles per thread
#pragma unroll
    for (int k = 0; k < 8; ++k) {
        const int t = tid * 8 + k;
        float fs = 0.f;
        int   is = 0;
#pragma unroll
        for (int j = 0; j < 4; ++j) {
            const float4 p = *reinterpret_cast<const float4*>(partial16 + t * 16 + j * 4);
            const int4   c = *reinterpret_cast<const int4*>(cnt16 + t * 16 + j * 4);
            fs += (p.x + p.y + p.z + p.w);
            is += (c.x + c.y + c.z + c.w);
        }
        contrib += fs;           // level-0 loss (already scaled by 1/4096)
        s0[t] = is;
    }
    __syncthreads();

    // level 1: 8^3 blocks, each aggregates 2^3 level-0 tiles (16^3 grid)
    {
        const int X = tid >> 6, Y = (tid >> 3) & 7, Z = tid & 7;
        int s = 0;
#pragma unroll
        for (int dx = 0; dx < 2; ++dx)
#pragma unroll
            for (int dy = 0; dy < 2; ++dy)
#pragma unroll
                for (int dz = 0; dz < 2; ++dz)
                    s += s0[((X * 2 + dx) * 16 + (Y * 2 + dy)) * 16 + (Z * 2 + dz)];
        s1[tid] = s;
        const int tot = 8 * 4096;
        const int c = (s == 0) ? 0 : ((s == tot) ? 1 : 2);
        contrib += nll3(l1 + tid * 3, c) * 32768.0f;      // 32^3
    }
    __syncthreads();
    // level 2: 4^3 blocks from 8^3 grid
    if (tid < 64) {
        const int X = tid >> 4, Y = (tid >> 2) & 3, Z = tid & 3;
        int s = 0;
#pragma unroll
        for (int dx = 0; dx < 2; ++dx)
#pragma unroll
            for (int dy = 0; dy < 2; ++dy)
#pragma unroll
                for (int dz = 0; dz < 2; ++dz)
                    s += s1[((X * 2 + dx) * 8 + (Y * 2 + dy)) * 8 + (Z * 2 + dz)];
        s2[tid] = s;
        const int tot = 64 * 4096;
        const int c = (s == 0) ? 0 : ((s == tot) ? 1 : 2);
        contrib += nll3(l2 + tid * 3, c) * 262144.0f;     // 64^3
    }
    __syncthreads();
    // level 3: 2^3 blocks from 4^3 grid
    if (tid < 8) {
        const int X = tid >> 2, Y = (tid >> 1) & 1, Z = tid & 1;
        int s = 0;
#pragma unroll
        for (int dx = 0; dx < 2; ++dx)
#pragma unroll
            for (int dy = 0; dy < 2; ++dy)
#pragma unroll
                for (int dz = 0; dz < 2; ++dz)
                    s += s2[((X * 2 + dx) * 4 + (Y * 2 + dy)) * 4 + (Z * 2 + dz)];
        s3[tid] = s;
        const int tot = 512 * 4096;
        const int c = (s == 0) ? 0 : ((s == tot) ? 1 : 2);
        contrib += nll3(l3 + tid * 3, c) * 2097152.0f;    // 128^3
    }
    __syncthreads();
    // level 4: 1 block = everything
    if (tid == 0) {
        int s = 0;
#pragma unroll
        for (int i = 0; i < 8; ++i) s += s3[i];
        const int tot = 4096 * 4096;
        const int c = (s == 0) ? 0 : ((s == tot) ? 1 : 2);
        contrib += nll3(l4, c) * 16777216.0f;             // 256^3
    }

    red[tid] = contrib;
    __syncthreads();
#pragma unroll
    for (int s = 256; s > 0; s >>= 1) {
        if (tid < s) red[tid] += red[tid + s];
        __syncthreads();
    }
    if (tid == 0) out[0] = red[0];
}

extern "C" void kernel_launch(void* const* d_in, const int* in_sizes, int n_in,
                              void* d_out, int out_size, void* d_ws, size_t ws_size,
                              hipStream_t stream) {
    const int*   gt    = (const int*)d_in[0];
    const float* dense = (const float*)d_in[1];
    const float* l1    = (const float*)d_in[2];
    const float* l2    = (const float*)d_in[3];
    const float* l3    = (const float*)d_in[4];
    const float* l4    = (const float*)d_in[5];
    float* out = (float*)d_out;

    float* partial16 = (float*)d_ws;                // 4096*16 floats (256 KB)
    int*   cnt16     = (int*)(partial16 + 4096*16); // 4096*16 ints  (256 KB)

    level0_kernel<<<2048, 256, 0, stream>>>(gt, dense, partial16, cnt16);
    levels_kernel<<<1, 512, 0, stream>>>(partial16, cnt16, l1, l2, l3, l4, out);
}

// Round 5
// 234.483 us; speedup vs baseline: 1.1005x; 1.1005x over previous
//
#include <hip/hip_runtime.h>

// Octree cross-entropy loss.
// D=256, BS=16 -> 4096 level-0 tiles of 16^3 voxels.
// Level 0: per-voxel 2-class CE, mean over tile, summed over tiles.
// Levels 1..4 (b = 32,64,128,256): 3-class CE (pure0/pure1/mixed) * b^3,
// class derived from per-16^3-tile popcounts of gt01 aggregated upward.
//
// R7 -> R8 changes:
//  - R7 grew the intermediate to [4096][16] and levels_kernel read it with
//    512-B lane stride (16 B used / 128-B line): ~4 MB fetched by one CU ->
//    levels ballooned and masked level0. R8: wave owns a HALF-TILE
//    (8 grid-stride iterations), accumulates in registers, ONE reduce, ONE
//    write -> intermediate is slot-major [2][4096] (64 KB), levels folds it
//    with coalesced float4 reads (~4 us).
//  - level0 keeps the copy-bench shape (2048x256, 32 waves/CU, no LDS, no
//    barriers, nontemporal logit loads) minus R7's per-iteration shuffle
//    overhead. Total time is now 157us fills + level0 + ~4us, so the bench
//    directly reveals level0.

typedef float v4f __attribute__((ext_vector_type(4)));

__device__ __forceinline__ float softplus(float x) {
    // log(1 + e^x), stable
    return fmaxf(x, 0.f) + __logf(1.f + __expf(-fabsf(x)));
}

__device__ __forceinline__ float nll3(const float* __restrict__ l, int c) {
    float a = l[0], b = l[1], d = l[2];
    float m = fmaxf(fmaxf(a, b), d);
    float lse = m + __logf(__expf(a - m) + __expf(b - m) + __expf(d - m));
    return lse - l[c];
}

// 2048 blocks x 256 threads = 8192 waves; wave W owns half-tile
// (tile = W>>1, half = W&1): 2048 voxels = 8 iterations x 64 lanes x 4 voxels.
__global__ __launch_bounds__(256, 8) void level0_kernel(
    const int* __restrict__ gt,        // [256^3], values +-1, x-major (x,y,z)
    const float* __restrict__ logits,  // [4096, 2, 4096]
    float* __restrict__ partial2,      // [2][4096] slot-major scaled NLL sums
    int* __restrict__ cnt2)            // [2][4096] slot-major popcounts
{
    const int lane = threadIdx.x & 63;
    const int W    = blockIdx.x * 4 + (threadIdx.x >> 6);  // 0..8191
    const int tile = W >> 1;
    const int half = W & 1;

    // logits: half h covers float4-units [h*512, h*512+512) of the tile
    const float* aptr = logits + (size_t)tile * 8192 + half * 2048;
    const float* bptr = aptr + 4096;

    // gt: unit off = half*512 + i*64 + lane -> voxel v = off*4:
    // ix = half*8 + i, iy = lane>>2, iz = (lane&3)*4
    const int bx = tile >> 8, by = (tile >> 4) & 15, bz = tile & 15;
    const int gbase = (bx << 20) + (half << 19) + (by << 12) + (bz << 4)
                    + ((lane >> 2) << 8) + ((lane & 3) << 2);

    float ls = 0.f;
    int   on = 0;
#pragma unroll
    for (int i = 0; i < 8; ++i) {
        const v4f a = __builtin_nontemporal_load(
            reinterpret_cast<const v4f*>(aptr + (i * 64 + lane) * 4));
        const v4f b = __builtin_nontemporal_load(
            reinterpret_cast<const v4f*>(bptr + (i * 64 + lane) * 4));
        const int4 g = *reinterpret_cast<const int4*>(gt + gbase + (i << 16));

        // 2-class CE: tgt=1 -> softplus(l0-l1); tgt=0 -> softplus(l1-l0)
        const float dx = a.x - b.x;
        const float dy = a.y - b.y;
        const float dz = a.z - b.z;
        const float dw = a.w - b.w;
        const int t0 = g.x > 0, t1 = g.y > 0, t2 = g.z > 0, t3 = g.w > 0;
        on += t0 + t1 + t2 + t3;
        ls += softplus(t0 ? dx : -dx)
            + softplus(t1 ? dy : -dy)
            + softplus(t2 ? dz : -dz)
            + softplus(t3 ? dw : -dw);
    }

    // one wave reduce, one write per half-tile (each slot written exactly once)
#pragma unroll
    for (int d = 32; d > 0; d >>= 1) {
        ls += __shfl_down(ls, d, 64);
        on += __shfl_down(on, d, 64);
    }
    if (lane == 0) {
        partial2[half * 4096 + tile] = ls * (1.0f / 4096.0f);
        cnt2[half * 4096 + tile]     = on;
    }
}

// Single block, 512 threads: fold 2 slots (coalesced), reduce level-0
// partials, hierarchical popcount aggregation, 3-class CE levels 1..4.
__global__ __launch_bounds__(512) void levels_kernel(
    const float* __restrict__ partial2, // [2][4096]
    const int* __restrict__ cnt2,       // [2][4096]
    const float* __restrict__ l1,       // [512,3]
    const float* __restrict__ l2,       // [64,3]
    const float* __restrict__ l3,       // [8,3]
    const float* __restrict__ l4,       // [1,3]
    float* __restrict__ out)
{
    __shared__ int   s0[4096];   // per-tile popcounts (16 KB)
    __shared__ int   s1[512];
    __shared__ int   s2[64];
    __shared__ int   s3[8];
    __shared__ float red[512];
    const int tid = threadIdx.x;
    float contrib = 0.f;

    // fold 2 slots per tile; 8 tiles per thread via 2x float4/int4 per slot
#pragma unroll
    for (int j = 0; j < 2; ++j) {
        const int t = tid * 8 + j * 4;
        const float4 p0 = *reinterpret_cast<const float4*>(partial2 + t);
        const float4 p1 = *reinterpret_cast<const float4*>(partial2 + 4096 + t);
        const int4   c0 = *reinterpret_cast<const int4*>(cnt2 + t);
        const int4   c1 = *reinterpret_cast<const int4*>(cnt2 + 4096 + t);
        contrib += (p0.x + p1.x) + (p0.y + p1.y) + (p0.z + p1.z) + (p0.w + p1.w);
        s0[t + 0] = c0.x + c1.x;
        s0[t + 1] = c0.y + c1.y;
        s0[t + 2] = c0.z + c1.z;
        s0[t + 3] = c0.w + c1.w;
    }
    __syncthreads();

    // level 1: 8^3 blocks, each aggregates 2^3 level-0 tiles (16^3 grid)
    {
        const int X = tid >> 6, Y = (tid >> 3) & 7, Z = tid & 7;
        int s = 0;
#pragma unroll
        for (int dx = 0; dx < 2; ++dx)
#pragma unroll
            for (int dy = 0; dy < 2; ++dy)
#pragma unroll
                for (int dz = 0; dz < 2; ++dz)
                    s += s0[((X * 2 + dx) * 16 + (Y * 2 + dy)) * 16 + (Z * 2 + dz)];
        s1[tid] = s;
        const int tot = 8 * 4096;
        const int c = (s == 0) ? 0 : ((s == tot) ? 1 : 2);
        contrib += nll3(l1 + tid * 3, c) * 32768.0f;      // 32^3
    }
    __syncthreads();
    // level 2: 4^3 blocks from 8^3 grid
    if (tid < 64) {
        const int X = tid >> 4, Y = (tid >> 2) & 3, Z = tid & 3;
        int s = 0;
#pragma unroll
        for (int dx = 0; dx < 2; ++dx)
#pragma unroll
            for (int dy = 0; dy < 2; ++dy)
#pragma unroll
                for (int dz = 0; dz < 2; ++dz)
                    s += s1[((X * 2 + dx) * 8 + (Y * 2 + dy)) * 8 + (Z * 2 + dz)];
        s2[tid] = s;
        const int tot = 64 * 4096;
        const int c = (s == 0) ? 0 : ((s == tot) ? 1 : 2);
        contrib += nll3(l2 + tid * 3, c) * 262144.0f;     // 64^3
    }
    __syncthreads();
    // level 3: 2^3 blocks from 4^3 grid
    if (tid < 8) {
        const int X = tid >> 2, Y = (tid >> 1) & 1, Z = tid & 1;
        int s = 0;
#pragma unroll
        for (int dx = 0; dx < 2; ++dx)
#pragma unroll
            for (int dy = 0; dy < 2; ++dy)
#pragma unroll
                for (int dz = 0; dz < 2; ++dz)
                    s += s2[((X * 2 + dx) * 4 + (Y * 2 + dy)) * 4 + (Z * 2 + dz)];
        s3[tid] = s;
        const int tot = 512 * 4096;
        const int c = (s == 0) ? 0 : ((s == tot) ? 1 : 2);
        contrib += nll3(l3 + tid * 3, c) * 2097152.0f;    // 128^3
    }
    __syncthreads();
    // level 4: 1 block = everything
    if (tid == 0) {
        int s = 0;
#pragma unroll
        for (int i = 0; i < 8; ++i) s += s3[i];
        const int tot = 4096 * 4096;
        const int c = (s == 0) ? 0 : ((s == tot) ? 1 : 2);
        contrib += nll3(l4, c) * 16777216.0f;             // 256^3
    }

    red[tid] = contrib;
    __syncthreads();
#pragma unroll
    for (int s = 256; s > 0; s >>= 1) {
        if (tid < s) red[tid] += red[tid + s];
        __syncthreads();
    }
    if (tid == 0) out[0] = red[0];
}

extern "C" void kernel_launch(void* const* d_in, const int* in_sizes, int n_in,
                              void* d_out, int out_size, void* d_ws, size_t ws_size,
                              hipStream_t stream) {
    const int*   gt    = (const int*)d_in[0];
    const float* dense = (const float*)d_in[1];
    const float* l1    = (const float*)d_in[2];
    const float* l2    = (const float*)d_in[3];
    const float* l3    = (const float*)d_in[4];
    const float* l4    = (const float*)d_in[5];
    float* out = (float*)d_out;

    float* partial2 = (float*)d_ws;              // [2][4096] floats (32 KB)
    int*   cnt2     = (int*)(partial2 + 8192);   // [2][4096] ints   (32 KB)

    level0_kernel<<<2048, 256, 0, stream>>>(gt, dense, partial2, cnt2);
    levels_kernel<<<1, 512, 0, stream>>>(partial2, cnt2, l1, l2, l3, l4, out);
}